// Round 7
// baseline (266.821 us; speedup 1.0000x reference)
//
#include <hip/hip_runtime.h>
#include <hip/hip_bf16.h>

#define T_TOK 2048
#define H_DIM 1024
#define I_DIM 512
#define E_NUM 64
#define TOPK  6
#define NROWS (T_TOK * TOPK)

typedef __attribute__((ext_vector_type(8))) short bf16x8;
typedef __attribute__((ext_vector_type(4))) float f32x4;
typedef __attribute__((ext_vector_type(2))) float f32x2;

union U4B8 { uint4 u; bf16x8 b; };

__device__ __forceinline__ unsigned int f2bf(float x) {
  unsigned int u = __float_as_uint(x);
  return (u + 0x7fffu + ((u >> 16) & 1u)) >> 16;   // RNE
}
__device__ __forceinline__ unsigned int pack2bf(float lo, float hi) {
  __hip_bfloat162 h = __float22bfloat162_rn(make_float2(lo, hi));
  return *reinterpret_cast<unsigned int*>(&h);     // v_cvt_pk_bf16_f32
}

// volatile asm load: compiler cannot sink it to the use site -> true prefetch
#define LOADF4(dst, p) \
  asm volatile("global_load_dwordx4 %0, %1, off" : "=v"(dst) : "v"(p))
#define LOADF2(dst, p) \
  asm volatile("global_load_dwordx2 %0, %1, off" : "=v"(dst) : "v"(p))

// counted wait: N must be a literal token
#define WAITVN(N) do { asm volatile("s_waitcnt vmcnt(" #N ")" ::: "memory"); \
  __builtin_amdgcn_sched_barrier(0); } while (0)

// producer barrier: drain LDS writes only; vmem loads stay in flight
#define BAR_LGKM() do { __builtin_amdgcn_sched_barrier(0); \
  asm volatile("s_waitcnt lgkmcnt(0)\n\ts_barrier" ::: "memory"); \
  __builtin_amdgcn_sched_barrier(0); } while (0)

// consumer barrier: no waitcnt at all
#define BAR_FREE() do { __builtin_amdgcn_sched_barrier(0); \
  asm volatile("s_barrier" ::: "memory"); \
  __builtin_amdgcn_sched_barrier(0); } while (0)

__device__ __forceinline__ void gload_lds16(const void* gsrc, void* ldst) {
  __builtin_amdgcn_global_load_lds(
      (const __attribute__((address_space(1))) unsigned int*)gsrc,
      (__attribute__((address_space(3))) unsigned int*)ldst, 16, 0, 0);
}

// ---------------- router: logits + sigmoid + grouped top-k + hs->bf16 ------
__global__ __launch_bounds__(64)
void router_kernel(const float* __restrict__ hs, const float* __restrict__ gw,
                   const float* __restrict__ eb, int* __restrict__ tk_id,
                   float* __restrict__ tk_w, unsigned short* __restrict__ xb)
{
  const int t = blockIdx.x;
  const int lane = threadIdx.x;          // lane == expert
  __shared__ float sh[H_DIM];
  const float4* hrow = (const float4*)(hs + (size_t)t * H_DIM);
  float4* sh4 = (float4*)sh;
  for (int i = lane; i < H_DIM / 4; i += 64) sh4[i] = hrow[i];
  __syncthreads();

  // emit bf16 copy of this token's row (consumed by gemm1 A-staging)
  {
    uint4* xrow = (uint4*)(xb + (size_t)t * H_DIM);
    #pragma unroll
    for (int f = 0; f < 2; ++f) {
      int i = lane + f * 64;                    // uint4 index 0..127
      float4 a = sh4[i * 2], b = sh4[i * 2 + 1];
      uint4 o;
      o.x = pack2bf(a.x, a.y); o.y = pack2bf(a.z, a.w);
      o.z = pack2bf(b.x, b.y); o.w = pack2bf(b.z, b.w);
      xrow[i] = o;
    }
  }

  const float* w = gw + (size_t)lane * H_DIM;
  float acc = 0.f;
  for (int k = 0; k < H_DIM; k += 4) {
    float4 wv = *(const float4*)(w + k);
    acc += sh[k] * wv.x + sh[k + 1] * wv.y + sh[k + 2] * wv.z + sh[k + 3] * wv.w;
  }
  const float score = 1.f / (1.f + expf(-acc));
  const float sfc = score + eb[lane];

  float m1v = sfc; int m1i = lane;
  #pragma unroll
  for (int d = 1; d < 8; d <<= 1) {
    float ov = __shfl_xor(m1v, d); int oi = __shfl_xor(m1i, d);
    if (ov > m1v || (ov == m1v && oi < m1i)) { m1v = ov; m1i = oi; }
  }
  float v2 = (lane == m1i) ? -INFINITY : sfc;
  #pragma unroll
  for (int d = 1; d < 8; d <<= 1) v2 = fmaxf(v2, __shfl_xor(v2, d));
  const float gscore = m1v + v2;

  const int myg = lane >> 3;
  int rank = 0;
  #pragma unroll
  for (int g = 0; g < 8; ++g) {
    float gs = __shfl(gscore, g * 8);
    if (gs > gscore || (gs == gscore && g < myg)) rank++;
  }
  float mv = (rank < 4) ? sfc : -INFINITY;

  int isel[TOPK]; float wsel[TOPK]; float wsum = 0.f;
  #pragma unroll
  for (int j = 0; j < TOPK; ++j) {
    float av = mv; int ai = lane;
    #pragma unroll
    for (int d = 1; d < 64; d <<= 1) {
      float ov = __shfl_xor(av, d); int oi = __shfl_xor(ai, d);
      if (ov > av || (ov == av && oi < ai)) { av = ov; ai = oi; }
    }
    float wj = __shfl(score, ai);
    isel[j] = ai; wsel[j] = wj; wsum += wj;
    if (lane == ai) mv = -INFINITY;
  }
  if (lane == 0) {
    float inv = 1.f / wsum;
    #pragma unroll
    for (int j = 0; j < TOPK; ++j) {
      tk_id[t * TOPK + j] = isel[j];
      tk_w[t * TOPK + j] = wsel[j] * inv;
    }
  }
}

// ---------------- counting-sort rows by expert ----------------
__global__ __launch_bounds__(1024)
void build_rows_kernel(const int* __restrict__ tk_id, const float* __restrict__ tk_w,
                       int* __restrict__ off, int* __restrict__ row_tok,
                       float* __restrict__ row_wt)
{
  __shared__ int cnt[E_NUM];
  __shared__ int base[E_NUM];
  const int tid = threadIdx.x;
  if (tid < E_NUM) cnt[tid] = 0;
  __syncthreads();
  for (int i = tid; i < NROWS; i += 1024) atomicAdd(&cnt[tk_id[i]], 1);
  __syncthreads();
  if (tid == 0) {
    int s = 0;
    for (int e = 0; e < E_NUM; ++e) { base[e] = s; off[e] = s; s += cnt[e]; }
    off[E_NUM] = s;
  }
  __syncthreads();
  if (tid < E_NUM) cnt[tid] = base[tid];
  __syncthreads();
  for (int i = tid; i < NROWS; i += 1024) {
    int e = tk_id[i];
    int p = atomicAdd(&cnt[e], 1);
    row_tok[p] = i / TOPK;
    row_wt[p] = tk_w[i];
  }
}

// ---------------- gemm1: act = silu(X@w1) * (X@w3) * wt  (bf16 out) --------
// BM=256 BN=64 BK=32, 512 threads / 8 waves (wave tile 64 rows x 32 cols).
// 2-deep B register pipeline at ZERO net VGPR cost (fBa[2]+fBb[2] == old fB[4]).
// Per-iter queue: entry [B(kt):2, A(kt):2, B(kt+1):2]; top vmcnt(4) retires
// B(kt); issue A(kt+1) then B(kt+2); pre-barrier vmcnt(6) retires A(kt) ->
// 6 ops ride across MFMA, B in flight 2 full iterations.
// LDS = 32K(A dbuf) + 4K + 4K = 40KB.
__global__ __launch_bounds__(512, 4)
void gemm1_kernel(const unsigned short* __restrict__ xb, const float* __restrict__ w1,
                  const float* __restrict__ w3, const int* __restrict__ off,
                  const int* __restrict__ row_tok, const float* __restrict__ row_wt,
                  unsigned short* __restrict__ act)
{
  const int e = blockIdx.x & 63;
  const int n0 = (blockIdx.x >> 6) * 64;
  const int r0 = off[e];
  const int R = off[e + 1] - r0;
  const int rt = blockIdx.y;
  if (rt * 256 >= R) return;

  __shared__ unsigned short sA2[2][256 * 32];  // 32KB dbuf, 4-chunk XOR swizzle
  __shared__ unsigned int sB1[4 * 64 * 4];     // 4KB [c=k>>3][n] 16B slots, swizzled
  __shared__ unsigned int sB3[4 * 64 * 4];     // 4KB

  const int tid = threadIdx.x;
  const int lane = tid & 63;
  const int wv = tid >> 6;                 // 0..7
  const int wm = wv >> 1, wn = wv & 1;     // wave tile: rows wm*64, cols wn*32
  const int l15 = lane & 15, lhi = lane >> 4;

  // A DMA map: wave fills rows wv*32..+31, 2 DMAs of 16 rows each.
  // LDS linear (lane*16B); source chunk pre-swizzled: s ^ ((ar^(ar>>2))&3).
  const unsigned short* asrc[2];
  #pragma unroll
  for (int i = 0; i < 2; ++i) {
    int ar = wv * 32 + i * 16 + (lane >> 2);
    int g = rt * 256 + ar; if (g >= R) g = R - 1;
    int tok = row_tok[r0 + g];
    int s = lane & 3;
    asrc[i] = xb + (size_t)tok * H_DIM + ((s ^ ((ar ^ (ar >> 2)) & 3)) << 3);
  }

  // B staging: tid<256 -> w1, tid>=256 -> w3; per thread 2 k-rows x 4 cols
  const int ht = tid & 255;
  const int qk = ht >> 4;                  // 0..15
  const int qn = ht & 15;
  const int k0 = qk * 2;
  const int nb = qn * 4;
  const int cB = qk >> 2;                  // k0>>3
  const int pr = qk & 3;                   // k-pair slot index
  const float* wp = ((tid < 256) ? w1 : w3) + (size_t)e * H_DIM * I_DIM + n0 + nb;
  char* const sBw = (char*)((tid < 256) ? sB1 : sB3);

  f32x4 acc1[4][2] = {};
  f32x4 acc3[4][2] = {};
  f32x4 fBa[2], fBb[2];

  char* const sB1c = (char*)sB1;
  char* const sB3c = (char*)sB3;

  // prologue order defines queue invariant: B(0), A(0), B(1)
  #pragma unroll
  for (int j = 0; j < 2; ++j) LOADF4(fBa[j], wp + (size_t)(k0 + j) * I_DIM);
  {
    unsigned short* dst = &sA2[0][(wv * 32) * 32];
    #pragma unroll
    for (int i = 0; i < 2; ++i) gload_lds16(asrc[i], dst + i * 16 * 32);
  }
  #pragma unroll
  for (int j = 0; j < 2; ++j) LOADF4(fBb[j], wp + (size_t)(32 + k0 + j) * I_DIM);

#define G1_ITER(KT, FB, TW, PW, ISSA, ISSB) \
  { \
    WAITVN(TW); \
    _Pragma("unroll") \
    for (int j = 0; j < 4; ++j) { \
      int n = nb + j; \
      unsigned int o16 = (unsigned)((cB * 64 + n) << 4) ^ (unsigned)(((n >> 3) & 7) << 4); \
      *(unsigned int*)(sBw + o16 + pr * 4) = pack2bf(FB[0][j], FB[1][j]); \
    } \
    if (ISSA) { \
      unsigned short* dst = &sA2[((KT) + 1) & 1][(wv * 32) * 32]; \
      _Pragma("unroll") \
      for (int i = 0; i < 2; ++i) gload_lds16(asrc[i] + ((KT) + 1) * 32, dst + i * 16 * 32); \
    } \
    if (ISSB) { \
      const float* bn = wp + (size_t)(((KT) + 2) * 32 + k0) * I_DIM; \
      _Pragma("unroll") \
      for (int j = 0; j < 2; ++j) LOADF4(FB[j], bn + (size_t)j * I_DIM); \
    } \
    WAITVN(PW); \
    BAR_LGKM(); \
    const char* sAb = (const char*)&sA2[(KT) & 1][0]; \
    __builtin_amdgcn_s_setprio(1); \
    { \
      bf16x8 af[4]; \
      _Pragma("unroll") \
      for (int mi = 0; mi < 4; ++mi) { \
        int m = wm * 64 + mi * 16 + l15; \
        U4B8 t; t.u = *(const uint4*)(sAb + m * 64 + ((lhi ^ ((m ^ (m >> 2)) & 3)) << 4)); \
        af[mi] = t.b; \
      } \
      _Pragma("unroll") \
      for (int ni = 0; ni < 2; ++ni) { \
        int n = wn * 32 + ni * 16 + l15; \
        unsigned int o = (unsigned)((lhi * 64 + n) << 4) ^ (unsigned)(((n >> 3) & 7) << 4); \
        U4B8 t1; t1.u = *(const uint4*)(sB1c + o); \
        U4B8 t3; t3.u = *(const uint4*)(sB3c + o); \
        _Pragma("unroll") \
        for (int mi = 0; mi < 4; ++mi) { \
          acc1[mi][ni] = __builtin_amdgcn_mfma_f32_16x16x32_bf16(af[mi], t1.b, acc1[mi][ni], 0, 0, 0); \
          acc3[mi][ni] = __builtin_amdgcn_mfma_f32_16x16x32_bf16(af[mi], t3.b, acc3[mi][ni], 0, 0, 0); \
        } \
      } \
    } \
    __builtin_amdgcn_s_setprio(0); \
    BAR_FREE(); \
  }

  for (int kt2 = 0; kt2 < 30; kt2 += 2) {
    G1_ITER(kt2, fBa, 4, 6, 1, 1);
    G1_ITER(kt2 + 1, fBb, 4, 6, 1, 1);
  }
  G1_ITER(30, fBa, 4, 4, 1, 0);
  G1_ITER(31, fBb, 2, 0, 0, 0);
#undef G1_ITER

  // epilogue: act = silu(g) * u * wt (bf16)
  #pragma unroll
  for (int mi = 0; mi < 4; ++mi) {
    #pragma unroll
    for (int j = 0; j < 4; ++j) {
      int row = wm * 64 + mi * 16 + lhi * 4 + j;
      int rg = rt * 256 + row;
      if (rg < R) {
        float wt = row_wt[r0 + rg];
        size_t rbase = (size_t)(r0 + rg) * I_DIM + n0 + wn * 32;
        #pragma unroll
        for (int ni = 0; ni < 2; ++ni) {
          float g = acc1[mi][ni][j];
          float u = acc3[mi][ni][j];
          float a = g / (1.f + __expf(-g)) * u * wt;
          act[rbase + ni * 16 + l15] = (unsigned short)f2bf(a);
        }
      }
    }
  }
}

// ---------------- gemm2: out[tok] += act @ w2 ----------------
// BM=256 BN=64 BK=32, 512 threads / 8 waves; same 2-deep pipeline
// (B = 2 x dwordx2 per thread, A = 2 gloads per wave). 16 iters.
// LDS = 32K + 4K + 1K = 37KB.
__global__ __launch_bounds__(512, 4)
void gemm2_kernel(const unsigned short* __restrict__ act, const float* __restrict__ w2,
                  const int* __restrict__ off, const int* __restrict__ row_tok,
                  float* __restrict__ out)
{
  const int e = blockIdx.x & 63;
  const int n0 = (blockIdx.x >> 6) * 64;
  const int r0 = off[e];
  const int R = off[e + 1] - r0;
  const int rt = blockIdx.y;
  if (rt * 256 >= R) return;

  __shared__ unsigned short sA2[2][256 * 32];  // 32KB dbuf
  __shared__ unsigned int sB[4 * 64 * 4];      // 4KB, swizzled
  __shared__ int s_tok[256];

  const int tid = threadIdx.x;
  if (tid < 256) {
    int r = rt * 256 + tid;
    int rr = (r < R) ? r : (R - 1);
    s_tok[tid] = row_tok[r0 + rr];
  }
  __syncthreads();

  const int lane = tid & 63;
  const int wv = tid >> 6;
  const int wm = wv >> 1, wn = wv & 1;
  const int l15 = lane & 15, lhi = lane >> 4;

  // A DMA map: wave fills rows wv*32..+31, 2 DMAs of 16 rows
  const unsigned short* asrc[2];
  #pragma unroll
  for (int i = 0; i < 2; ++i) {
    int ar = wv * 32 + i * 16 + (lane >> 2);
    int g = rt * 256 + ar; if (g >= R) g = R - 1;
    int s = lane & 3;
    asrc[i] = act + (size_t)(r0 + g) * I_DIM + ((s ^ ((ar ^ (ar >> 2)) & 3)) << 3);
  }

  // B staging: 512 threads, 2 k-rows x 2 cols each (dwordx2)
  const int qk = tid >> 5;                 // 0..15
  const int qn = tid & 31;
  const int k0 = qk * 2;
  const int nb = qn * 2;
  const int cB = qk >> 2;
  const int pr = qk & 3;
  const float* w2p = w2 + (size_t)e * I_DIM * H_DIM + n0 + nb;

  f32x4 acc[4][2] = {};
  f32x2 fBa[2], fBb[2];

  char* const sBc = (char*)sB;

  // prologue: B(0), A(0), B(1)
  #pragma unroll
  for (int j = 0; j < 2; ++j) LOADF2(fBa[j], w2p + (size_t)(k0 + j) * H_DIM);
  {
    unsigned short* dst = &sA2[0][(wv * 32) * 32];
    #pragma unroll
    for (int i = 0; i < 2; ++i) gload_lds16(asrc[i], dst + i * 16 * 32);
  }
  #pragma unroll
  for (int j = 0; j < 2; ++j) LOADF2(fBb[j], w2p + (size_t)(32 + k0 + j) * H_DIM);

#define G2_ITER(KT, FB, TW, PW, ISSA, ISSB) \
  { \
    WAITVN(TW); \
    _Pragma("unroll") \
    for (int j = 0; j < 2; ++j) { \
      int n = nb + j; \
      unsigned int o16 = (unsigned)((cB * 64 + n) << 4) ^ (unsigned)(((n >> 3) & 7) << 4); \
      *(unsigned int*)(sBc + o16 + pr * 4) = pack2bf(FB[0][j], FB[1][j]); \
    } \
    if (ISSA) { \
      unsigned short* dst = &sA2[((KT) + 1) & 1][(wv * 32) * 32]; \
      _Pragma("unroll") \
      for (int i = 0; i < 2; ++i) gload_lds16(asrc[i] + ((KT) + 1) * 32, dst + i * 16 * 32); \
    } \
    if (ISSB) { \
      const float* bn = w2p + (size_t)(((KT) + 2) * 32 + k0) * H_DIM; \
      _Pragma("unroll") \
      for (int j = 0; j < 2; ++j) LOADF2(FB[j], bn + (size_t)j * H_DIM); \
    } \
    WAITVN(PW); \
    BAR_LGKM(); \
    const char* sAb = (const char*)&sA2[(KT) & 1][0]; \
    __builtin_amdgcn_s_setprio(1); \
    { \
      bf16x8 af[4]; \
      _Pragma("unroll") \
      for (int mi = 0; mi < 4; ++mi) { \
        int m = wm * 64 + mi * 16 + l15; \
        U4B8 t; t.u = *(const uint4*)(sAb + m * 64 + ((lhi ^ ((m ^ (m >> 2)) & 3)) << 4)); \
        af[mi] = t.b; \
      } \
      _Pragma("unroll") \
      for (int ni = 0; ni < 2; ++ni) { \
        int n = wn * 32 + ni * 16 + l15; \
        unsigned int o = (unsigned)((lhi * 64 + n) << 4) ^ (unsigned)(((n >> 3) & 7) << 4); \
        U4B8 tb; tb.u = *(const uint4*)(sBc + o); \
        _Pragma("unroll") \
        for (int mi = 0; mi < 4; ++mi) \
          acc[mi][ni] = __builtin_amdgcn_mfma_f32_16x16x32_bf16(af[mi], tb.b, acc[mi][ni], 0, 0, 0); \
      } \
    } \
    __builtin_amdgcn_s_setprio(0); \
    BAR_FREE(); \
  }

  for (int kt2 = 0; kt2 < 14; kt2 += 2) {
    G2_ITER(kt2, fBa, 4, 6, 1, 1);
    G2_ITER(kt2 + 1, fBb, 4, 6, 1, 1);
  }
  G2_ITER(14, fBa, 4, 4, 1, 0);
  G2_ITER(15, fBb, 2, 0, 0, 0);
#undef G2_ITER

  // epilogue: scatter-add to token rows
  #pragma unroll
  for (int mi = 0; mi < 4; ++mi) {
    #pragma unroll
    for (int j = 0; j < 4; ++j) {
      int row = wm * 64 + mi * 16 + lhi * 4 + j;
      if (rt * 256 + row < R) {
        float* ob = out + (size_t)s_tok[row] * H_DIM + n0 + wn * 32;
        #pragma unroll
        for (int ni = 0; ni < 2; ++ni) {
          atomicAdd(ob + ni * 16 + l15, acc[mi][ni][j]);
        }
      }
    }
  }
}

extern "C" void kernel_launch(void* const* d_in, const int* in_sizes, int n_in,
                              void* d_out, int out_size, void* d_ws, size_t ws_size,
                              hipStream_t stream)
{
  const float* hs = (const float*)d_in[0];
  const float* gw = (const float*)d_in[1];
  const float* eb = (const float*)d_in[2];
  const float* w1 = (const float*)d_in[3];
  const float* w3 = (const float*)d_in[4];
  const float* w2 = (const float*)d_in[5];
  float* out = (float*)d_out;

  char* ws = (char*)d_ws;
  int*   tk_id   = (int*)(ws);                          // 49152 B
  float* tk_w    = (float*)(ws + 49152);                // 49152 B
  int*   off     = (int*)(ws + 98304);                  // 512 B (65 used)
  int*   row_tok = (int*)(ws + 98816);                  // 49152 B
  float* row_wt  = (float*)(ws + 147968);               // 49152 B
  unsigned short* xb  = (unsigned short*)(ws + 197120); // 4 MB bf16 hs
  unsigned short* act = (unsigned short*)(ws + 197120 + 4194304); // 12.58 MB

  hipMemsetAsync(out, 0, (size_t)T_TOK * H_DIM * sizeof(float), stream);
  hipLaunchKernelGGL(router_kernel, dim3(T_TOK), dim3(64), 0, stream,
                     hs, gw, eb, tk_id, tk_w, xb);
  hipLaunchKernelGGL(build_rows_kernel, dim3(1), dim3(1024), 0, stream,
                     tk_id, tk_w, off, row_tok, row_wt);
  hipLaunchKernelGGL(gemm1_kernel, dim3(8 * E_NUM, 8, 1), dim3(512), 0, stream,
                     xb, w1, w3, off, row_tok, row_wt, act);
  hipLaunchKernelGGL(gemm2_kernel, dim3(16 * E_NUM, 8, 1), dim3(512), 0, stream,
                     act, w2, off, row_tok, out);
}

// Round 9
// 262.793 us; speedup vs baseline: 1.0153x; 1.0153x over previous
//
#include <hip/hip_runtime.h>
#include <hip/hip_bf16.h>

#define T_TOK 2048
#define H_DIM 1024
#define I_DIM 512
#define E_NUM 64
#define TOPK  6
#define NROWS (T_TOK * TOPK)

typedef __attribute__((ext_vector_type(8))) short bf16x8;
typedef __attribute__((ext_vector_type(4))) float f32x4;

union U4B8 { uint4 u; bf16x8 b; };

__device__ __forceinline__ unsigned int f2bf(float x) {
  unsigned int u = __float_as_uint(x);
  return (u + 0x7fffu + ((u >> 16) & 1u)) >> 16;   // RNE
}
__device__ __forceinline__ unsigned int pack2bf(float lo, float hi) {
  __hip_bfloat162 h = __float22bfloat162_rn(make_float2(lo, hi));
  return *reinterpret_cast<unsigned int*>(&h);     // v_cvt_pk_bf16_f32
}

// volatile asm load: compiler cannot sink it to the use site -> true prefetch
#define LOADF4(dst, p) \
  asm volatile("global_load_dwordx4 %0, %1, off" : "=v"(dst) : "v"(p))

// counted wait: N must be a literal token
#define WAITVN(N) do { asm volatile("s_waitcnt vmcnt(" #N ")" ::: "memory"); \
  __builtin_amdgcn_sched_barrier(0); } while (0)

// producer barrier: drain LDS writes only; vmem loads stay in flight
#define BAR_LGKM() do { __builtin_amdgcn_sched_barrier(0); \
  asm volatile("s_waitcnt lgkmcnt(0)\n\ts_barrier" ::: "memory"); \
  __builtin_amdgcn_sched_barrier(0); } while (0)

// consumer barrier: no waitcnt at all
#define BAR_FREE() do { __builtin_amdgcn_sched_barrier(0); \
  asm volatile("s_barrier" ::: "memory"); \
  __builtin_amdgcn_sched_barrier(0); } while (0)

__device__ __forceinline__ void gload_lds16(const void* gsrc, void* ldst) {
  __builtin_amdgcn_global_load_lds(
      (const __attribute__((address_space(1))) unsigned int*)gsrc,
      (__attribute__((address_space(3))) unsigned int*)ldst, 16, 0, 0);
}

// ---------------- router: logits + sigmoid + grouped top-k + hs->bf16 ------
__global__ __launch_bounds__(64)
void router_kernel(const float* __restrict__ hs, const float* __restrict__ gw,
                   const float* __restrict__ eb, int* __restrict__ tk_id,
                   float* __restrict__ tk_w, unsigned short* __restrict__ xb)
{
  const int t = blockIdx.x;
  const int lane = threadIdx.x;          // lane == expert
  __shared__ float sh[H_DIM];
  const float4* hrow = (const float4*)(hs + (size_t)t * H_DIM);
  float4* sh4 = (float4*)sh;
  for (int i = lane; i < H_DIM / 4; i += 64) sh4[i] = hrow[i];
  __syncthreads();

  // emit bf16 copy of this token's row (consumed by gemm1 A-staging)
  {
    uint4* xrow = (uint4*)(xb + (size_t)t * H_DIM);
    #pragma unroll
    for (int f = 0; f < 2; ++f) {
      int i = lane + f * 64;                    // uint4 index 0..127
      float4 a = sh4[i * 2], b = sh4[i * 2 + 1];
      uint4 o;
      o.x = pack2bf(a.x, a.y); o.y = pack2bf(a.z, a.w);
      o.z = pack2bf(b.x, b.y); o.w = pack2bf(b.z, b.w);
      xrow[i] = o;
    }
  }

  const float* w = gw + (size_t)lane * H_DIM;
  float acc = 0.f;
  for (int k = 0; k < H_DIM; k += 4) {
    float4 wv = *(const float4*)(w + k);
    acc += sh[k] * wv.x + sh[k + 1] * wv.y + sh[k + 2] * wv.z + sh[k + 3] * wv.w;
  }
  const float score = 1.f / (1.f + expf(-acc));
  const float sfc = score + eb[lane];

  float m1v = sfc; int m1i = lane;
  #pragma unroll
  for (int d = 1; d < 8; d <<= 1) {
    float ov = __shfl_xor(m1v, d); int oi = __shfl_xor(m1i, d);
    if (ov > m1v || (ov == m1v && oi < m1i)) { m1v = ov; m1i = oi; }
  }
  float v2 = (lane == m1i) ? -INFINITY : sfc;
  #pragma unroll
  for (int d = 1; d < 8; d <<= 1) v2 = fmaxf(v2, __shfl_xor(v2, d));
  const float gscore = m1v + v2;

  const int myg = lane >> 3;
  int rank = 0;
  #pragma unroll
  for (int g = 0; g < 8; ++g) {
    float gs = __shfl(gscore, g * 8);
    if (gs > gscore || (gs == gscore && g < myg)) rank++;
  }
  float mv = (rank < 4) ? sfc : -INFINITY;

  int isel[TOPK]; float wsel[TOPK]; float wsum = 0.f;
  #pragma unroll
  for (int j = 0; j < TOPK; ++j) {
    float av = mv; int ai = lane;
    #pragma unroll
    for (int d = 1; d < 64; d <<= 1) {
      float ov = __shfl_xor(av, d); int oi = __shfl_xor(ai, d);
      if (ov > av || (ov == av && oi < ai)) { av = ov; ai = oi; }
    }
    float wj = __shfl(score, ai);
    isel[j] = ai; wsel[j] = wj; wsum += wj;
    if (lane == ai) mv = -INFINITY;
  }
  if (lane == 0) {
    float inv = 1.f / wsum;
    #pragma unroll
    for (int j = 0; j < TOPK; ++j) {
      tk_id[t * TOPK + j] = isel[j];
      tk_w[t * TOPK + j] = wsel[j] * inv;
    }
  }
}

// ---------------- counting-sort rows by expert ----------------
__global__ __launch_bounds__(1024)
void build_rows_kernel(const int* __restrict__ tk_id, const float* __restrict__ tk_w,
                       int* __restrict__ off, int* __restrict__ row_tok,
                       float* __restrict__ row_wt)
{
  __shared__ int cnt[E_NUM];
  __shared__ int base[E_NUM];
  const int tid = threadIdx.x;
  if (tid < E_NUM) cnt[tid] = 0;
  __syncthreads();
  for (int i = tid; i < NROWS; i += 1024) atomicAdd(&cnt[tk_id[i]], 1);
  __syncthreads();
  if (tid == 0) {
    int s = 0;
    for (int e = 0; e < E_NUM; ++e) { base[e] = s; off[e] = s; s += cnt[e]; }
    off[E_NUM] = s;
  }
  __syncthreads();
  if (tid < E_NUM) cnt[tid] = base[tid];
  __syncthreads();
  for (int i = tid; i < NROWS; i += 1024) {
    int e = tk_id[i];
    int p = atomicAdd(&cnt[e], 1);
    row_tok[p] = i / TOPK;
    row_wt[p] = tk_w[i];
  }
}

// ---------------- gemm1: act = silu(X@w1) * (X@w3) * wt  (bf16 out) --------
// BM=128 BN=128 BK=32, 512 threads / 8 waves (wave tile 64 rows x 32 cols;
// wm=wv>>2, wn=wv&3). DRAM-row fix: 128-col panels = 512B per 2KB weight row.
// Register budget (the R8 lesson): 64 AGPR acc + fB[4]=16 VGPR + addressing
// fits the 128-reg cap of __launch_bounds__(512,4) -> no spills (R6-proven).
// Schedule = R6's passing skeleton: 1-deep B prefetch, counted waits, A dbuf
// via global_load_lds issued AFTER BAR_LGKM into the alternate buffer.
// Queue invariant: entry [B(kt):4, A(kt):1]; TW vmcnt(1) retires B(kt);
// issue B(kt+1); PW vmcnt(4) retires A(kt); barrier; issue A(kt+1).
// LDS = 16K(A dbuf) + 8K + 8K = 32KB.
__global__ __launch_bounds__(512, 4)
void gemm1_kernel(const unsigned short* __restrict__ xb, const float* __restrict__ w1,
                  const float* __restrict__ w3, const int* __restrict__ off,
                  const int* __restrict__ row_tok, const float* __restrict__ row_wt,
                  unsigned short* __restrict__ act)
{
  const int e = blockIdx.x & 63;
  const int n0 = (blockIdx.x >> 6) * 128;
  const int r0 = off[e];
  const int R = off[e + 1] - r0;
  const int rt = blockIdx.y;
  if (rt * 128 >= R) return;

  __shared__ unsigned short sA2[2][128 * 32];  // 16KB dbuf, 4-chunk XOR swizzle
  __shared__ unsigned int sB1[4 * 128 * 4];    // 8KB [c=k>>3][n] 16B slots, swizzled
  __shared__ unsigned int sB3[4 * 128 * 4];    // 8KB

  const int tid = threadIdx.x;
  const int lane = tid & 63;
  const int wv = tid >> 6;                 // 0..7
  const int wm = wv >> 2, wn = wv & 3;     // wave tile: rows wm*64, cols wn*32
  const int l15 = lane & 15, lhi = lane >> 4;

  // A DMA map: wave fills rows wv*16..+15 (1 gload_lds16: lane -> row lane>>2,
  // chunk lane&3). Source chunk pre-swizzled: s ^ ((ar^(ar>>2))&3).
  const unsigned short* asrc;
  {
    int ar = wv * 16 + (lane >> 2);
    int g = rt * 128 + ar; if (g >= R) g = R - 1;
    int tok = row_tok[r0 + g];
    int s = lane & 3;
    asrc = xb + (size_t)tok * H_DIM + ((s ^ ((ar ^ (ar >> 2)) & 3)) << 3);
  }

  // B staging: tid<256 -> w1, tid>=256 -> w3; per thread 2 k-rows x 8 cols
  const int ht = tid & 255;
  const int qk = ht >> 4;                  // 0..15
  const int qn = ht & 15;
  const int k0 = qk * 2;
  const int nb = qn * 8;
  const int cB = k0 >> 3;                  // 0..3
  const int pr = (k0 >> 1) & 3;            // k-pair slot index
  const float* wp = ((tid < 256) ? w1 : w3) + (size_t)e * H_DIM * I_DIM + n0 + nb;
  char* const sBw = (char*)((tid < 256) ? sB1 : sB3);

  f32x4 acc1[4][2] = {};
  f32x4 acc3[4][2] = {};
  f32x4 fB[4];

  char* const sB1c = (char*)sB1;
  char* const sB3c = (char*)sB3;

  // prologue: B(0):4 then A(0):1 -> queue [B0:4, A0:1]
  LOADF4(fB[0], wp + (size_t)k0 * I_DIM);
  LOADF4(fB[1], wp + (size_t)k0 * I_DIM + 4);
  LOADF4(fB[2], wp + (size_t)(k0 + 1) * I_DIM);
  LOADF4(fB[3], wp + (size_t)(k0 + 1) * I_DIM + 4);
  gload_lds16(asrc, &sA2[0][(wv * 16) * 32]);

  for (int kt = 0; kt < 32; ++kt) {
    WAITVN(1);                             // B(kt) retired; A(kt) in flight
    // pack + write B tile (each thread: one matrix, 2 k-rows x 8 cols)
    #pragma unroll
    for (int j = 0; j < 4; ++j) {
      int n = nb + j;
      unsigned int o16 = (unsigned)((cB * 128 + n) << 4) ^ (unsigned)(((n >> 3) & 7) << 4);
      *(unsigned int*)(sBw + o16 + pr * 4) = pack2bf(fB[0][j], fB[2][j]);
    }
    #pragma unroll
    for (int j = 0; j < 4; ++j) {
      int n = nb + 4 + j;
      unsigned int o16 = (unsigned)((cB * 128 + n) << 4) ^ (unsigned)(((n >> 3) & 7) << 4);
      *(unsigned int*)(sBw + o16 + pr * 4) = pack2bf(fB[1][j], fB[3][j]);
    }
    // issue B(kt+1): register dest, stays in flight across MFMA + barriers
    if (kt < 31) {
      const float* bn = wp + (size_t)((kt + 1) * 32 + k0) * I_DIM;
      LOADF4(fB[0], bn);
      LOADF4(fB[1], bn + 4);
      LOADF4(fB[2], bn + I_DIM);
      LOADF4(fB[3], bn + I_DIM + 4);
    }
    // retire A(kt); B(kt+1) stays in flight
    if (kt < 31) { WAITVN(4); } else { WAITVN(0); }
    BAR_LGKM();
    // DMA A(kt+1) into other buffer (all waves past MFMA(kt-1) reads)
    if (kt < 31) {
      gload_lds16(asrc + (kt + 1) * 32, &sA2[(kt + 1) & 1][(wv * 16) * 32]);
    }
    // MFMA on buf[kt&1] + sB1/sB3
    const char* sAb = (const char*)&sA2[kt & 1][0];
    __builtin_amdgcn_s_setprio(1);
    {
      bf16x8 af[4];
      #pragma unroll
      for (int mi = 0; mi < 4; ++mi) {
        int m = wm * 64 + mi * 16 + l15;
        U4B8 t; t.u = *(const uint4*)(sAb + m * 64 + ((lhi ^ ((m ^ (m >> 2)) & 3)) << 4));
        af[mi] = t.b;
      }
      #pragma unroll
      for (int ni = 0; ni < 2; ++ni) {
        int n = wn * 32 + ni * 16 + l15;
        unsigned int o = (unsigned)((lhi * 128 + n) << 4) ^ (unsigned)(((n >> 3) & 7) << 4);
        U4B8 t1; t1.u = *(const uint4*)(sB1c + o);
        U4B8 t3; t3.u = *(const uint4*)(sB3c + o);
        #pragma unroll
        for (int mi = 0; mi < 4; ++mi) {
          acc1[mi][ni] = __builtin_amdgcn_mfma_f32_16x16x32_bf16(af[mi], t1.b, acc1[mi][ni], 0, 0, 0);
          acc3[mi][ni] = __builtin_amdgcn_mfma_f32_16x16x32_bf16(af[mi], t3.b, acc3[mi][ni], 0, 0, 0);
        }
      }
    }
    __builtin_amdgcn_s_setprio(0);
    BAR_FREE();
  }

  // epilogue: act = silu(g) * u * wt (bf16)
  #pragma unroll
  for (int mi = 0; mi < 4; ++mi) {
    #pragma unroll
    for (int j = 0; j < 4; ++j) {
      int row = wm * 64 + mi * 16 + lhi * 4 + j;
      int rg = rt * 128 + row;
      if (rg < R) {
        float wt = row_wt[r0 + rg];
        size_t rbase = (size_t)(r0 + rg) * I_DIM + n0 + wn * 32;
        #pragma unroll
        for (int ni = 0; ni < 2; ++ni) {
          float g = acc1[mi][ni][j];
          float u = acc3[mi][ni][j];
          float a = g / (1.f + __expf(-g)) * u * wt;
          act[rbase + ni * 16 + l15] = (unsigned short)f2bf(a);
        }
      }
    }
  }
}

// ---------------- gemm2: out[tok] += act @ w2 ----------------
// BM=128 BN=128 BK=32, 512 threads / 8 waves; 1024 live blocks.
// Same R6-proven schedule; B = 2 loads/iter (2 k-rows x 4 cols/thread).
// Queue: entry [B(kt):2, A(kt):1]; TW vmcnt(1); PW vmcnt(2) (last 0).
// LDS = 16K(A dbuf) + 8K(B) + 0.5K = 24.5KB. Regs: 32 AGPR + fB[2]=8 VGPR.
__global__ __launch_bounds__(512, 4)
void gemm2_kernel(const unsigned short* __restrict__ act, const float* __restrict__ w2,
                  const int* __restrict__ off, const int* __restrict__ row_tok,
                  float* __restrict__ out)
{
  const int e = blockIdx.x & 63;
  const int n0 = (blockIdx.x >> 6) * 128;
  const int r0 = off[e];
  const int R = off[e + 1] - r0;
  const int rt = blockIdx.y;
  if (rt * 128 >= R) return;

  __shared__ unsigned short sA2[2][128 * 32];  // 16KB dbuf
  __shared__ unsigned int sB[4 * 128 * 4];     // 8KB, swizzled
  __shared__ int s_tok[128];

  const int tid = threadIdx.x;
  if (tid < 128) {
    int r = rt * 128 + tid;
    int rr = (r < R) ? r : (R - 1);
    s_tok[tid] = row_tok[r0 + rr];
  }
  __syncthreads();

  const int lane = tid & 63;
  const int wv = tid >> 6;
  const int wm = wv >> 2, wn = wv & 3;
  const int l15 = lane & 15, lhi = lane >> 4;

  // A DMA map: wave fills rows wv*16..+15, 1 gload_lds16 per iter
  const unsigned short* asrc;
  {
    int ar = wv * 16 + (lane >> 2);
    int g = rt * 128 + ar; if (g >= R) g = R - 1;
    int s = lane & 3;
    asrc = act + (size_t)(r0 + g) * I_DIM + ((s ^ ((ar ^ (ar >> 2)) & 3)) << 3);
  }

  // B staging: per thread 2 k-rows x 4 cols
  const int qk = tid >> 5;                 // 0..15
  const int qn = tid & 31;
  const int k0 = qk * 2;
  const int nb = qn * 4;
  const int cB = k0 >> 3;
  const int pr = (k0 >> 1) & 3;
  const float* w2p = w2 + (size_t)e * I_DIM * H_DIM + n0 + nb;

  f32x4 acc[4][2] = {};
  f32x4 fB[2];

  char* const sBc = (char*)sB;

  // prologue: B(0):2 then A(0):1
  LOADF4(fB[0], w2p + (size_t)k0 * H_DIM);
  LOADF4(fB[1], w2p + (size_t)(k0 + 1) * H_DIM);
  gload_lds16(asrc, &sA2[0][(wv * 16) * 32]);

  for (int kt = 0; kt < 16; ++kt) {
    WAITVN(1);                             // B(kt) retired; A(kt) in flight
    #pragma unroll
    for (int j = 0; j < 4; ++j) {
      int n = nb + j;
      unsigned int o16 = (unsigned)((cB * 128 + n) << 4) ^ (unsigned)(((n >> 3) & 7) << 4);
      *(unsigned int*)(sBc + o16 + pr * 4) = pack2bf(fB[0][j], fB[1][j]);
    }
    if (kt < 15) {
      const float* bn = w2p + (size_t)((kt + 1) * 32 + k0) * H_DIM;
      LOADF4(fB[0], bn);
      LOADF4(fB[1], bn + H_DIM);
    }
    if (kt < 15) { WAITVN(2); } else { WAITVN(0); }
    BAR_LGKM();
    if (kt < 15) {
      gload_lds16(asrc + (kt + 1) * 32, &sA2[(kt + 1) & 1][(wv * 16) * 32]);
    }
    const char* sAb = (const char*)&sA2[kt & 1][0];
    __builtin_amdgcn_s_setprio(1);
    {
      bf16x8 af[4];
      #pragma unroll
      for (int mi = 0; mi < 4; ++mi) {
        int m = wm * 64 + mi * 16 + l15;
        U4B8 t; t.u = *(const uint4*)(sAb + m * 64 + ((lhi ^ ((m ^ (m >> 2)) & 3)) << 4));
        af[mi] = t.b;
      }
      #pragma unroll
      for (int ni = 0; ni < 2; ++ni) {
        int n = wn * 32 + ni * 16 + l15;
        unsigned int o = (unsigned)((lhi * 128 + n) << 4) ^ (unsigned)(((n >> 3) & 7) << 4);
        U4B8 tb; tb.u = *(const uint4*)(sBc + o);
        #pragma unroll
        for (int mi = 0; mi < 4; ++mi)
          acc[mi][ni] = __builtin_amdgcn_mfma_f32_16x16x32_bf16(af[mi], tb.b, acc[mi][ni], 0, 0, 0);
      }
    }
    __builtin_amdgcn_s_setprio(0);
    BAR_FREE();
  }

  // epilogue: scatter-add to token rows
  #pragma unroll
  for (int mi = 0; mi < 4; ++mi) {
    #pragma unroll
    for (int j = 0; j < 4; ++j) {
      int row = wm * 64 + mi * 16 + lhi * 4 + j;
      if (rt * 128 + row < R) {
        float* ob = out + (size_t)s_tok[row] * H_DIM + n0 + wn * 32;
        #pragma unroll
        for (int ni = 0; ni < 2; ++ni) {
          atomicAdd(ob + ni * 16 + l15, acc[mi][ni][j]);
        }
      }
    }
  }
}

extern "C" void kernel_launch(void* const* d_in, const int* in_sizes, int n_in,
                              void* d_out, int out_size, void* d_ws, size_t ws_size,
                              hipStream_t stream)
{
  const float* hs = (const float*)d_in[0];
  const float* gw = (const float*)d_in[1];
  const float* eb = (const float*)d_in[2];
  const float* w1 = (const float*)d_in[3];
  const float* w3 = (const float*)d_in[4];
  const float* w2 = (const float*)d_in[5];
  float* out = (float*)d_out;

  char* ws = (char*)d_ws;
  int*   tk_id   = (int*)(ws);                          // 49152 B
  float* tk_w    = (float*)(ws + 49152);                // 49152 B
  int*   off     = (int*)(ws + 98304);                  // 512 B (65 used)
  int*   row_tok = (int*)(ws + 98816);                  // 49152 B
  float* row_wt  = (float*)(ws + 147968);               // 49152 B
  unsigned short* xb  = (unsigned short*)(ws + 197120); // 4 MB bf16 hs
  unsigned short* act = (unsigned short*)(ws + 197120 + 4194304); // 12.58 MB

  hipMemsetAsync(out, 0, (size_t)T_TOK * H_DIM * sizeof(float), stream);
  hipLaunchKernelGGL(router_kernel, dim3(T_TOK), dim3(64), 0, stream,
                     hs, gw, eb, tk_id, tk_w, xb);
  hipLaunchKernelGGL(build_rows_kernel, dim3(1), dim3(1024), 0, stream,
                     tk_id, tk_w, off, row_tok, row_wt);
  hipLaunchKernelGGL(gemm1_kernel, dim3(4 * E_NUM, 8, 1), dim3(512), 0, stream,
                     xb, w1, w3, off, row_tok, row_wt, act);
  hipLaunchKernelGGL(gemm2_kernel, dim3(8 * E_NUM, 8, 1), dim3(512), 0, stream,
                     act, w2, off, row_tok, out);
}

// Round 10
// 241.770 us; speedup vs baseline: 1.1036x; 1.0870x over previous
//
#include <hip/hip_runtime.h>
#include <hip/hip_bf16.h>

#define T_TOK 2048
#define H_DIM 1024
#define I_DIM 512
#define E_NUM 64
#define TOPK  6
#define NROWS (T_TOK * TOPK)

typedef __attribute__((ext_vector_type(8))) short bf16x8;
typedef __attribute__((ext_vector_type(4))) float f32x4;

union U4B8 { uint4 u; bf16x8 b; };

__device__ __forceinline__ unsigned int f2bf(float x) {
  unsigned int u = __float_as_uint(x);
  return (u + 0x7fffu + ((u >> 16) & 1u)) >> 16;   // RNE
}
__device__ __forceinline__ unsigned int pack2bf(float lo, float hi) {
  __hip_bfloat162 h = __float22bfloat162_rn(make_float2(lo, hi));
  return *reinterpret_cast<unsigned int*>(&h);     // v_cvt_pk_bf16_f32
}

// volatile asm load: compiler cannot sink it to the use site -> true prefetch
#define LOADF4(dst, p) \
  asm volatile("global_load_dwordx4 %0, %1, off" : "=v"(dst) : "v"(p))

// counted wait: N must be a literal token
#define WAITVN(N) do { asm volatile("s_waitcnt vmcnt(" #N ")" ::: "memory"); \
  __builtin_amdgcn_sched_barrier(0); } while (0)

// producer barrier: drain LDS writes only; vmem loads stay in flight
#define BAR_LGKM() do { __builtin_amdgcn_sched_barrier(0); \
  asm volatile("s_waitcnt lgkmcnt(0)\n\ts_barrier" ::: "memory"); \
  __builtin_amdgcn_sched_barrier(0); } while (0)

// consumer barrier: no waitcnt at all
#define BAR_FREE() do { __builtin_amdgcn_sched_barrier(0); \
  asm volatile("s_barrier" ::: "memory"); \
  __builtin_amdgcn_sched_barrier(0); } while (0)

__device__ __forceinline__ void gload_lds16(const void* gsrc, void* ldst) {
  __builtin_amdgcn_global_load_lds(
      (const __attribute__((address_space(1))) unsigned int*)gsrc,
      (__attribute__((address_space(3))) unsigned int*)ldst, 16, 0, 0);
}

// ---------------- router: 2 tokens/block (wave = token) -------------------
__global__ __launch_bounds__(128)
void router_kernel(const float* __restrict__ hs, const float* __restrict__ gw,
                   const float* __restrict__ eb, int* __restrict__ tk_id,
                   float* __restrict__ tk_w, unsigned short* __restrict__ xb)
{
  const int wv = threadIdx.x >> 6;
  const int lane = threadIdx.x & 63;     // lane == expert
  const int t = blockIdx.x * 2 + wv;
  __shared__ float sh[2][H_DIM];
  const float4* hrow = (const float4*)(hs + (size_t)t * H_DIM);
  float4* sh4 = (float4*)sh[wv];
  for (int i = lane; i < H_DIM / 4; i += 64) sh4[i] = hrow[i];
  __syncthreads();

  // emit bf16 copy of this token's row (consumed by gemm1 A-staging)
  {
    uint4* xrow = (uint4*)(xb + (size_t)t * H_DIM);
    #pragma unroll
    for (int f = 0; f < 2; ++f) {
      int i = lane + f * 64;                    // uint4 index 0..127
      float4 a = sh4[i * 2], b = sh4[i * 2 + 1];
      uint4 o;
      o.x = pack2bf(a.x, a.y); o.y = pack2bf(a.z, a.w);
      o.z = pack2bf(b.x, b.y); o.w = pack2bf(b.z, b.w);
      xrow[i] = o;
    }
  }

  const float* w = gw + (size_t)lane * H_DIM;
  const float* shp = sh[wv];
  float acc = 0.f;
  for (int k = 0; k < H_DIM; k += 4) {
    float4 wvv = *(const float4*)(w + k);
    acc += shp[k] * wvv.x + shp[k + 1] * wvv.y + shp[k + 2] * wvv.z + shp[k + 3] * wvv.w;
  }
  const float score = 1.f / (1.f + expf(-acc));
  const float sfc = score + eb[lane];

  float m1v = sfc; int m1i = lane;
  #pragma unroll
  for (int d = 1; d < 8; d <<= 1) {
    float ov = __shfl_xor(m1v, d); int oi = __shfl_xor(m1i, d);
    if (ov > m1v || (ov == m1v && oi < m1i)) { m1v = ov; m1i = oi; }
  }
  float v2 = (lane == m1i) ? -INFINITY : sfc;
  #pragma unroll
  for (int d = 1; d < 8; d <<= 1) v2 = fmaxf(v2, __shfl_xor(v2, d));
  const float gscore = m1v + v2;

  const int myg = lane >> 3;
  int rank = 0;
  #pragma unroll
  for (int g = 0; g < 8; ++g) {
    float gs = __shfl(gscore, g * 8);
    if (gs > gscore || (gs == gscore && g < myg)) rank++;
  }
  float mv = (rank < 4) ? sfc : -INFINITY;

  int isel[TOPK]; float wsel[TOPK]; float wsum = 0.f;
  #pragma unroll
  for (int j = 0; j < TOPK; ++j) {
    float av = mv; int ai = lane;
    #pragma unroll
    for (int d = 1; d < 64; d <<= 1) {
      float ov = __shfl_xor(av, d); int oi = __shfl_xor(ai, d);
      if (ov > av || (ov == av && oi < ai)) { av = ov; ai = oi; }
    }
    float wj = __shfl(score, ai);
    isel[j] = ai; wsel[j] = wj; wsum += wj;
    if (lane == ai) mv = -INFINITY;
  }
  if (lane == 0) {
    float inv = 1.f / wsum;
    #pragma unroll
    for (int j = 0; j < TOPK; ++j) {
      tk_id[t * TOPK + j] = isel[j];
      tk_w[t * TOPK + j] = wsel[j] * inv;
    }
  }
}

// ---------------- counting-sort rows by expert ----------------
__global__ __launch_bounds__(1024)
void build_rows_kernel(const int* __restrict__ tk_id, const float* __restrict__ tk_w,
                       int* __restrict__ off, int* __restrict__ row_tok,
                       float* __restrict__ row_wt, int* __restrict__ inv)
{
  __shared__ int cnt[E_NUM];
  __shared__ int base[E_NUM];
  const int tid = threadIdx.x;
  if (tid < E_NUM) cnt[tid] = 0;
  __syncthreads();
  for (int i = tid; i < NROWS; i += 1024) atomicAdd(&cnt[tk_id[i]], 1);
  __syncthreads();
  if (tid == 0) {
    int s = 0;
    for (int e = 0; e < E_NUM; ++e) { base[e] = s; off[e] = s; s += cnt[e]; }
    off[E_NUM] = s;
  }
  __syncthreads();
  if (tid < E_NUM) cnt[tid] = base[tid];
  __syncthreads();
  for (int i = tid; i < NROWS; i += 1024) {
    int e = tk_id[i];
    int p = atomicAdd(&cnt[e], 1);
    row_tok[p] = i / TOPK;
    row_wt[p] = tk_w[i];
    inv[i] = p;                      // token-slot -> sorted row (for combine)
  }
}

// ---------------- gemm1: act = silu(X@w1) * (X@w3) * wt  (bf16 out) --------
// UNCHANGED from R9 (passed, 126us, 1.3TB/s -- the converged control).
// BM=128 BN=128 BK=32, 512 threads / 8 waves.
__global__ __launch_bounds__(512, 4)
void gemm1_kernel(const unsigned short* __restrict__ xb, const float* __restrict__ w1,
                  const float* __restrict__ w3, const int* __restrict__ off,
                  const int* __restrict__ row_tok, const float* __restrict__ row_wt,
                  unsigned short* __restrict__ act)
{
  const int e = blockIdx.x & 63;
  const int n0 = (blockIdx.x >> 6) * 128;
  const int r0 = off[e];
  const int R = off[e + 1] - r0;
  const int rt = blockIdx.y;
  if (rt * 128 >= R) return;

  __shared__ unsigned short sA2[2][128 * 32];  // 16KB dbuf, 4-chunk XOR swizzle
  __shared__ unsigned int sB1[4 * 128 * 4];    // 8KB [c=k>>3][n] 16B slots, swizzled
  __shared__ unsigned int sB3[4 * 128 * 4];    // 8KB

  const int tid = threadIdx.x;
  const int lane = tid & 63;
  const int wv = tid >> 6;                 // 0..7
  const int wm = wv >> 2, wn = wv & 3;     // wave tile: rows wm*64, cols wn*32
  const int l15 = lane & 15, lhi = lane >> 4;

  const unsigned short* asrc;
  {
    int ar = wv * 16 + (lane >> 2);
    int g = rt * 128 + ar; if (g >= R) g = R - 1;
    int tok = row_tok[r0 + g];
    int s = lane & 3;
    asrc = xb + (size_t)tok * H_DIM + ((s ^ ((ar ^ (ar >> 2)) & 3)) << 3);
  }

  const int ht = tid & 255;
  const int qk = ht >> 4;                  // 0..15
  const int qn = ht & 15;
  const int k0 = qk * 2;
  const int nb = qn * 8;
  const int cB = k0 >> 3;                  // 0..3
  const int pr = (k0 >> 1) & 3;            // k-pair slot index
  const float* wp = ((tid < 256) ? w1 : w3) + (size_t)e * H_DIM * I_DIM + n0 + nb;
  char* const sBw = (char*)((tid < 256) ? sB1 : sB3);

  f32x4 acc1[4][2] = {};
  f32x4 acc3[4][2] = {};
  f32x4 fB[4];

  char* const sB1c = (char*)sB1;
  char* const sB3c = (char*)sB3;

  // prologue: B(0):4 then A(0):1 -> queue [B0:4, A0:1]
  LOADF4(fB[0], wp + (size_t)k0 * I_DIM);
  LOADF4(fB[1], wp + (size_t)k0 * I_DIM + 4);
  LOADF4(fB[2], wp + (size_t)(k0 + 1) * I_DIM);
  LOADF4(fB[3], wp + (size_t)(k0 + 1) * I_DIM + 4);
  gload_lds16(asrc, &sA2[0][(wv * 16) * 32]);

  for (int kt = 0; kt < 32; ++kt) {
    WAITVN(1);                             // B(kt) retired; A(kt) in flight
    #pragma unroll
    for (int j = 0; j < 4; ++j) {
      int n = nb + j;
      unsigned int o16 = (unsigned)((cB * 128 + n) << 4) ^ (unsigned)(((n >> 3) & 7) << 4);
      *(unsigned int*)(sBw + o16 + pr * 4) = pack2bf(fB[0][j], fB[2][j]);
    }
    #pragma unroll
    for (int j = 0; j < 4; ++j) {
      int n = nb + 4 + j;
      unsigned int o16 = (unsigned)((cB * 128 + n) << 4) ^ (unsigned)(((n >> 3) & 7) << 4);
      *(unsigned int*)(sBw + o16 + pr * 4) = pack2bf(fB[1][j], fB[3][j]);
    }
    if (kt < 31) {
      const float* bn = wp + (size_t)((kt + 1) * 32 + k0) * I_DIM;
      LOADF4(fB[0], bn);
      LOADF4(fB[1], bn + 4);
      LOADF4(fB[2], bn + I_DIM);
      LOADF4(fB[3], bn + I_DIM + 4);
    }
    if (kt < 31) { WAITVN(4); } else { WAITVN(0); }
    BAR_LGKM();
    if (kt < 31) {
      gload_lds16(asrc + (kt + 1) * 32, &sA2[(kt + 1) & 1][(wv * 16) * 32]);
    }
    const char* sAb = (const char*)&sA2[kt & 1][0];
    __builtin_amdgcn_s_setprio(1);
    {
      bf16x8 af[4];
      #pragma unroll
      for (int mi = 0; mi < 4; ++mi) {
        int m = wm * 64 + mi * 16 + l15;
        U4B8 t; t.u = *(const uint4*)(sAb + m * 64 + ((lhi ^ ((m ^ (m >> 2)) & 3)) << 4));
        af[mi] = t.b;
      }
      #pragma unroll
      for (int ni = 0; ni < 2; ++ni) {
        int n = wn * 32 + ni * 16 + l15;
        unsigned int o = (unsigned)((lhi * 128 + n) << 4) ^ (unsigned)(((n >> 3) & 7) << 4);
        U4B8 t1; t1.u = *(const uint4*)(sB1c + o);
        U4B8 t3; t3.u = *(const uint4*)(sB3c + o);
        #pragma unroll
        for (int mi = 0; mi < 4; ++mi) {
          acc1[mi][ni] = __builtin_amdgcn_mfma_f32_16x16x32_bf16(af[mi], t1.b, acc1[mi][ni], 0, 0, 0);
          acc3[mi][ni] = __builtin_amdgcn_mfma_f32_16x16x32_bf16(af[mi], t3.b, acc3[mi][ni], 0, 0, 0);
        }
      }
    }
    __builtin_amdgcn_s_setprio(0);
    BAR_FREE();
  }

  // epilogue: act = silu(g) * u * wt (bf16)
  #pragma unroll
  for (int mi = 0; mi < 4; ++mi) {
    #pragma unroll
    for (int j = 0; j < 4; ++j) {
      int row = wm * 64 + mi * 16 + lhi * 4 + j;
      int rg = rt * 128 + row;
      if (rg < R) {
        float wt = row_wt[r0 + rg];
        size_t rbase = (size_t)(r0 + rg) * I_DIM + n0 + wn * 32;
        #pragma unroll
        for (int ni = 0; ni < 2; ++ni) {
          float g = acc1[mi][ni][j];
          float u = acc3[mi][ni][j];
          float a = g / (1.f + __expf(-g)) * u * wt;
          act[rbase + ni * 16 + l15] = (unsigned short)f2bf(a);
        }
      }
    }
  }
}

// ---------------- gemm2: slot_out[row] = act[row] @ w2  (bf16, NO atomics) --
// Same R9 GEMM body; epilogue now writes coalesced bf16 slot rows (weights
// already applied in gemm1). combine_kernel sums 6 slots per token.
__global__ __launch_bounds__(512, 4)
void gemm2_kernel(const unsigned short* __restrict__ act, const float* __restrict__ w2,
                  const int* __restrict__ off, unsigned short* __restrict__ slot_out)
{
  const int e = blockIdx.x & 63;
  const int n0 = (blockIdx.x >> 6) * 128;
  const int r0 = off[e];
  const int R = off[e + 1] - r0;
  const int rt = blockIdx.y;
  if (rt * 128 >= R) return;

  __shared__ unsigned short sA2[2][128 * 32];  // 16KB dbuf
  __shared__ unsigned int sB[4 * 128 * 4];     // 8KB, swizzled

  const int tid = threadIdx.x;
  const int lane = tid & 63;
  const int wv = tid >> 6;
  const int wm = wv >> 2, wn = wv & 3;
  const int l15 = lane & 15, lhi = lane >> 4;

  const unsigned short* asrc;
  {
    int ar = wv * 16 + (lane >> 2);
    int g = rt * 128 + ar; if (g >= R) g = R - 1;
    int s = lane & 3;
    asrc = act + (size_t)(r0 + g) * I_DIM + ((s ^ ((ar ^ (ar >> 2)) & 3)) << 3);
  }

  const int qk = tid >> 5;                 // 0..15
  const int qn = tid & 31;
  const int k0 = qk * 2;
  const int nb = qn * 4;
  const int cB = k0 >> 3;
  const int pr = (k0 >> 1) & 3;
  const float* w2p = w2 + (size_t)e * I_DIM * H_DIM + n0 + nb;

  f32x4 acc[4][2] = {};
  f32x4 fB[2];

  char* const sBc = (char*)sB;

  // prologue: B(0):2 then A(0):1
  LOADF4(fB[0], w2p + (size_t)k0 * H_DIM);
  LOADF4(fB[1], w2p + (size_t)(k0 + 1) * H_DIM);
  gload_lds16(asrc, &sA2[0][(wv * 16) * 32]);

  for (int kt = 0; kt < 16; ++kt) {
    WAITVN(1);                             // B(kt) retired; A(kt) in flight
    #pragma unroll
    for (int j = 0; j < 4; ++j) {
      int n = nb + j;
      unsigned int o16 = (unsigned)((cB * 128 + n) << 4) ^ (unsigned)(((n >> 3) & 7) << 4);
      *(unsigned int*)(sBc + o16 + pr * 4) = pack2bf(fB[0][j], fB[1][j]);
    }
    if (kt < 15) {
      const float* bn = w2p + (size_t)((kt + 1) * 32 + k0) * H_DIM;
      LOADF4(fB[0], bn);
      LOADF4(fB[1], bn + H_DIM);
    }
    if (kt < 15) { WAITVN(2); } else { WAITVN(0); }
    BAR_LGKM();
    if (kt < 15) {
      gload_lds16(asrc + (kt + 1) * 32, &sA2[(kt + 1) & 1][(wv * 16) * 32]);
    }
    const char* sAb = (const char*)&sA2[kt & 1][0];
    __builtin_amdgcn_s_setprio(1);
    {
      bf16x8 af[4];
      #pragma unroll
      for (int mi = 0; mi < 4; ++mi) {
        int m = wm * 64 + mi * 16 + l15;
        U4B8 t; t.u = *(const uint4*)(sAb + m * 64 + ((lhi ^ ((m ^ (m >> 2)) & 3)) << 4));
        af[mi] = t.b;
      }
      #pragma unroll
      for (int ni = 0; ni < 2; ++ni) {
        int n = wn * 32 + ni * 16 + l15;
        unsigned int o = (unsigned)((lhi * 128 + n) << 4) ^ (unsigned)(((n >> 3) & 7) << 4);
        U4B8 tb; tb.u = *(const uint4*)(sBc + o);
        #pragma unroll
        for (int mi = 0; mi < 4; ++mi)
          acc[mi][ni] = __builtin_amdgcn_mfma_f32_16x16x32_bf16(af[mi], tb.b, acc[mi][ni], 0, 0, 0);
      }
    }
    __builtin_amdgcn_s_setprio(0);
    BAR_FREE();
  }

  // epilogue: coalesced bf16 slot-row stores (no atomics)
  #pragma unroll
  for (int mi = 0; mi < 4; ++mi) {
    #pragma unroll
    for (int j = 0; j < 4; ++j) {
      int row = wm * 64 + mi * 16 + lhi * 4 + j;
      int rg = rt * 128 + row;
      if (rg < R) {
        unsigned short* ob = slot_out + (size_t)(r0 + rg) * H_DIM + n0 + wn * 32;
        #pragma unroll
        for (int ni = 0; ni < 2; ++ni) {
          ob[ni * 16 + l15] = (unsigned short)f2bf(acc[mi][ni][j]);
        }
      }
    }
  }
}

// ---------------- combine: out[t] = sum_j slot_out[inv[t*6+j]] -------------
__global__ __launch_bounds__(256)
void combine_kernel(const unsigned short* __restrict__ slot_out,
                    const int* __restrict__ inv, float* __restrict__ out)
{
  const int t = blockIdx.x;
  const int c = threadIdx.x;            // 4 cols per thread
  int rows[TOPK];
  #pragma unroll
  for (int j = 0; j < TOPK; ++j) rows[j] = inv[t * TOPK + j];
  float a0 = 0.f, a1 = 0.f, a2 = 0.f, a3 = 0.f;
  #pragma unroll
  for (int j = 0; j < TOPK; ++j) {
    const ushort4 v = *(const ushort4*)(slot_out + (size_t)rows[j] * H_DIM + c * 4);
    a0 += __uint_as_float((unsigned)v.x << 16);
    a1 += __uint_as_float((unsigned)v.y << 16);
    a2 += __uint_as_float((unsigned)v.z << 16);
    a3 += __uint_as_float((unsigned)v.w << 16);
  }
  *(float4*)(out + (size_t)t * H_DIM + c * 4) = make_float4(a0, a1, a2, a3);
}

extern "C" void kernel_launch(void* const* d_in, const int* in_sizes, int n_in,
                              void* d_out, int out_size, void* d_ws, size_t ws_size,
                              hipStream_t stream)
{
  const float* hs = (const float*)d_in[0];
  const float* gw = (const float*)d_in[1];
  const float* eb = (const float*)d_in[2];
  const float* w1 = (const float*)d_in[3];
  const float* w3 = (const float*)d_in[4];
  const float* w2 = (const float*)d_in[5];
  float* out = (float*)d_out;

  char* ws = (char*)d_ws;
  int*   tk_id   = (int*)(ws);                          // 49152 B
  float* tk_w    = (float*)(ws + 49152);                // 49152 B
  int*   off     = (int*)(ws + 98304);                  // 512 B (65 used)
  int*   row_tok = (int*)(ws + 98816);                  // 49152 B
  float* row_wt  = (float*)(ws + 147968);               // 49152 B
  int*   inv     = (int*)(ws + 197120);                 // 49152 B
  unsigned short* xb  = (unsigned short*)(ws + 246272); // 4 MB bf16 hs
  unsigned short* act = (unsigned short*)(ws + 246272 + 4194304);      // 12.58 MB
  unsigned short* slot_out = (unsigned short*)(ws + 246272 + 4194304 + 12582912); // 25.17 MB

  hipLaunchKernelGGL(router_kernel, dim3(T_TOK / 2), dim3(128), 0, stream,
                     hs, gw, eb, tk_id, tk_w, xb);
  hipLaunchKernelGGL(build_rows_kernel, dim3(1), dim3(1024), 0, stream,
                     tk_id, tk_w, off, row_tok, row_wt, inv);
  hipLaunchKernelGGL(gemm1_kernel, dim3(4 * E_NUM, 8, 1), dim3(512), 0, stream,
                     xb, w1, w3, off, row_tok, row_wt, act);
  hipLaunchKernelGGL(gemm2_kernel, dim3(8 * E_NUM, 8, 1), dim3(512), 0, stream,
                     act, w2, off, slot_out);
  hipLaunchKernelGGL(combine_kernel, dim3(T_TOK), dim3(256), 0, stream,
                     slot_out, inv, out);
}